// Round 1
// baseline (291.412 us; speedup 1.0000x reference)
//
#include <hip/hip_runtime.h>

#define IN_F    512
#define OUT_F   10240
#define NPROJ   6
#define THREADS 256
#define PER_T   (OUT_F / THREADS)   // 40 outputs per thread

// One block per batch row.
//  - stage inp row (512 f32 = 2KB) in LDS
//  - each thread computes 40 activations (6 LDS gathers each), kept in registers
//  - exact kth-largest (k = hash_length) via 4-pass radix select on float bits
//    (all activations are non-negative -> uint bit order == float order)
//  - predicated coalesced store
__global__ __launch_bounds__(THREADS) void flyhash_wta_kernel(
    const float* __restrict__ inp,
    const int*   __restrict__ proj,
    const int*   __restrict__ hlen,
    float*       __restrict__ out)
{
    __shared__ float    s_row[IN_F];
    __shared__ unsigned s_hist[256];
    __shared__ unsigned s_bcast[2];

    const int b = blockIdx.x;
    const int t = threadIdx.x;

    // --- stage input row: 256 threads x float2 = 512 floats ---
    ((float2*)s_row)[t] = ((const float2*)(inp + (size_t)b * IN_F))[t];
    __syncthreads();

    // --- gather-sum activations into registers ---
    float act[PER_T];
#pragma unroll
    for (int i = 0; i < PER_T; ++i) {
        const int o = t + i * THREADS;
        const int2* ip = (const int2*)(proj + (size_t)o * NPROJ);
        const int2 p0 = ip[0];
        const int2 p1 = ip[1];
        const int2 p2 = ip[2];
        act[i] = ((s_row[p0.x] + s_row[p0.y]) +
                  (s_row[p1.x] + s_row[p1.y])) +
                 (s_row[p2.x] + s_row[p2.y]);
    }

    // --- radix select: exact k-th largest over this row's OUT_F activations ---
    int k = hlen[0];                 // hash_length (32)
    unsigned prefix = 0;
    for (int d = 3; d >= 0; --d) {
        s_hist[t] = 0;               // THREADS == 256 bins
        __syncthreads();
        const unsigned shift = (unsigned)d * 8u;
        const unsigned hm = (d == 3) ? 0u : (0xFFFFFFFFu << (shift + 8u));
#pragma unroll
        for (int i = 0; i < PER_T; ++i) {
            const unsigned bits = __float_as_uint(act[i]);
            if ((bits & hm) == prefix)
                atomicAdd(&s_hist[(bits >> shift) & 255u], 1u);
        }
        __syncthreads();
        if (t == 0) {
            int cum = 0, bsel = 255;
            for (; bsel > 0; --bsel) {
                cum += (int)s_hist[bsel];
                if (cum >= k) break;
            }
            if (cum < k) cum += (int)s_hist[0];          // bsel == 0 fallthrough
            s_bcast[0] = prefix | ((unsigned)bsel << shift);
            s_bcast[1] = (unsigned)(k - (cum - (int)s_hist[bsel]));
        }
        __syncthreads();
        prefix = s_bcast[0];
        k = (int)s_bcast[1];
        __syncthreads();
    }
    const float kth = __uint_as_float(prefix);

    // --- predicated coalesced store ---
    float* orow = out + (size_t)b * OUT_F;
#pragma unroll
    for (int i = 0; i < PER_T; ++i) {
        const int o = t + i * THREADS;
        const float v = act[i];
        orow[o] = (v >= kth) ? v : 0.0f;
    }
}

extern "C" void kernel_launch(void* const* d_in, const int* in_sizes, int n_in,
                              void* d_out, int out_size, void* d_ws, size_t ws_size,
                              hipStream_t stream) {
    const float* inp  = (const float*)d_in[0];
    const int*   proj = (const int*)d_in[1];
    const int*   hlen = (const int*)d_in[2];
    float*       out  = (float*)d_out;

    const int batch = in_sizes[0] / IN_F;   // 4096

    hipLaunchKernelGGL(flyhash_wta_kernel, dim3(batch), dim3(THREADS), 0, stream,
                       inp, proj, hlen, out);
}

// Round 2
// 80.276 us; speedup vs baseline: 3.6301x; 3.6301x over previous
//
#include <hip/hip_runtime.h>

#define IN_F     512
#define OUT_F    10240
#define NPROJ    6
#define THREADS  256
#define PER_T    (OUT_F / THREADS)   // 40 outputs per thread
#define NBINS    256
#define MAXLVL   5
#define CAND_CAP 64

// One block per batch row.
//  - stage inp row (2KB) in LDS
//  - each thread: 40 activations (6 LDS gathers each) in registers
//  - selection: block max -> linear 256-bin histogram -> parallel suffix scan
//    -> iterative 256x bin refinement (monotone keys) -> exact rank select
//    over <=64 candidates. Exact same selection set as reference top_k.
__global__ __launch_bounds__(THREADS) void flyhash_wta_kernel(
    const float* __restrict__ inp,
    const int*   __restrict__ proj,
    const int*   __restrict__ hlen,
    float*       __restrict__ out)
{
    __shared__ float    s_row[IN_F];
    __shared__ unsigned s_hist[NBINS];
    __shared__ float    s_wmax[4];
    __shared__ unsigned s_wsum[4];
    __shared__ unsigned s_bc[3];
    __shared__ float    s_cand[CAND_CAP];
    __shared__ unsigned s_ccount;
    __shared__ float    s_kth;

    const int b    = blockIdx.x;
    const int t    = threadIdx.x;
    const int lane = t & 63;
    const int wave = t >> 6;

    // --- stage input row ---
    ((float2*)s_row)[t] = ((const float2*)(inp + (size_t)b * IN_F))[t];
    __syncthreads();

    // --- gather-sum activations (same summation order as round 1: absmax 0) ---
    float act[PER_T];
#pragma unroll
    for (int i = 0; i < PER_T; ++i) {
        const int o = t + i * THREADS;
        const int2* ip = (const int2*)(proj + (size_t)o * NPROJ);
        const int2 p0 = ip[0];
        const int2 p1 = ip[1];
        const int2 p2 = ip[2];
        act[i] = ((s_row[p0.x] + s_row[p0.y]) +
                  (s_row[p1.x] + s_row[p1.y])) +
                 (s_row[p2.x] + s_row[p2.y]);
    }

    // --- block max (all activations are >= 0) ---
    float m = 0.0f;
#pragma unroll
    for (int i = 0; i < PER_T; ++i) m = fmaxf(m, act[i]);
#pragma unroll
    for (int d = 1; d < 64; d <<= 1) m = fmaxf(m, __shfl_xor(m, d));
    if (lane == 0) s_wmax[wave] = m;
    __syncthreads();
    const float M = fmaxf(fmaxf(s_wmax[0], s_wmax[1]),
                          fmaxf(s_wmax[2], s_wmax[3]));

    float kth = 0.0f;
    if (M > 0.0f) {
        int need = hlen[0];                       // rank from the top (k)
        unsigned long long alive = (1ull << PER_T) - 1ull;
        float r[PER_T];                           // monotone residual keys
        const float scale0 = 255.0f / M;
#pragma unroll
        for (int i = 0; i < PER_T; ++i) r[i] = act[i] * scale0;

        unsigned cnt_in_bin = 0;
        for (int level = 0; level < MAXLVL; ++level) {
            s_hist[t] = 0u;
            __syncthreads();

            // histogram alive values; linear bins -> atomics spread by density
#pragma unroll
            for (int i = 0; i < PER_T; ++i) {
                if (alive & (1ull << i)) {
                    int bin = (int)r[i];
                    bin = (bin > NBINS - 1) ? (NBINS - 1) : bin;
                    atomicAdd(&s_hist[bin], 1u);
                }
            }
            __syncthreads();

            // parallel suffix scan: S(t) = sum of hist bins >= t
            const unsigned h = s_hist[t];
            unsigned s = h;
#pragma unroll
            for (int d = 1; d < 64; d <<= 1) {
                const unsigned o = __shfl_down(s, d);
                if (lane + d < 64) s += o;
            }
            if (lane == 0) s_wsum[wave] = s;
            __syncthreads();
            for (int w = wave + 1; w < 4; ++w) s += s_wsum[w];
            const int S = (int)s;

            // unique thread whose bin contains the need-th largest
            if (h > 0u && S >= need && (S - (int)h) < need) {
                s_bc[0] = (unsigned)t;            // bin B
                s_bc[1] = (unsigned)(S - (int)h); // count strictly above bin B
                s_bc[2] = h;                      // count inside bin B
            }
            __syncthreads();
            const int B = (int)s_bc[0];
            need      -= (int)s_bc[1];
            cnt_in_bin = s_bc[2];

            // narrow alive set to bin B; refine residual keys (monotone)
#pragma unroll
            for (int i = 0; i < PER_T; ++i) {
                if (alive & (1ull << i)) {
                    int bin = (int)r[i];
                    bin = (bin > NBINS - 1) ? (NBINS - 1) : bin;
                    if (bin != B) alive &= ~(1ull << i);
                    else          r[i] = (r[i] - (float)B) * 256.0f;
                }
            }
            if (cnt_in_bin <= CAND_CAP) break;
        }

        // --- exact rank select over the candidates ---
        if (t == 0) s_ccount = 0u;
        __syncthreads();
#pragma unroll
        for (int i = 0; i < PER_T; ++i) {
            if (alive & (1ull << i)) {
                const unsigned idx = atomicAdd(&s_ccount, 1u);
                if (idx < CAND_CAP) s_cand[idx] = act[i];
            }
        }
        __syncthreads();
        const unsigned c = s_ccount;
        if (c > CAND_CAP) {
            // >64 values inside a sub-ulp range after MAXLVL refinements:
            // all bit-identical -> any of them is the kth value
            if (t == 0) s_kth = s_cand[0];
        } else if (t < (int)c) {
            const float v = s_cand[t];
            int gt = 0, eq = 0;
            for (unsigned j = 0; j < c; ++j) {
                const float u = s_cand[j];
                gt += (u > v);
                eq += (u == v);
            }
            if (gt < need && gt + eq >= need) s_kth = v;  // ties write same value
        }
        __syncthreads();
        kth = s_kth;
    }

    // --- predicated coalesced store ---
    float* orow = out + (size_t)b * OUT_F;
#pragma unroll
    for (int i = 0; i < PER_T; ++i) {
        const int o = t + i * THREADS;
        const float v = act[i];
        orow[o] = (v >= kth) ? v : 0.0f;
    }
}

extern "C" void kernel_launch(void* const* d_in, const int* in_sizes, int n_in,
                              void* d_out, int out_size, void* d_ws, size_t ws_size,
                              hipStream_t stream) {
    const float* inp  = (const float*)d_in[0];
    const int*   proj = (const int*)d_in[1];
    const int*   hlen = (const int*)d_in[2];
    float*       out  = (float*)d_out;

    const int batch = in_sizes[0] / IN_F;   // 4096

    hipLaunchKernelGGL(flyhash_wta_kernel, dim3(batch), dim3(THREADS), 0, stream,
                       inp, proj, hlen, out);
}